// Round 10
// baseline (209.996 us; speedup 1.0000x reference)
//
#include <hip/hip_runtime.h>
#include <hip/hip_bf16.h>
#include <stdint.h>

// ResonanceAttention on MI355X (gfx950) — round 19.
// R18 post-mortem: XCD-partitioning the GEMMs ~= +1.3us (L2-thrash theory
// wrong). Budget now closes: gemm_qkv = 25.8 GFLOP at the m97-structure's
// small-shape rate (~300-500 TF, m102 curve) ~= 55-80us — as big as flash.
// The stall: at K=1024, 32 barrier+drain windows for only 16 MFMA each.
// R19: FUSE Q and K ops (they share the whole A operand hs): one block stages
// As once + both Bq,Bk -> 6 glds16 + 2 barriers + 32 MFMA per K-step.
// Barriers per unit work halve; A-traffic halves. V unchanged. One kernel,
// 512 blocks (256 fused-QK + 256 V). VGPR ~195 < 256 (launch_bounds(256,2)),
// 2 blk/CU, no spill by construction (R13/R15 lesson).
// Pipeline: cvt5 -> gemm_qkv -> flash_full -> gemm_out_bf.

#define PRIME_SCALE 0.047245559126654356f  // 1/sqrt(7*64)
#define LOG2E       1.4426950408889634f
#define LN2         0.6931471805599453f
#define QSCALE      (PRIME_SCALE * LOG2E)  // Q pre-scaled so softmax uses exp2
#define BLEND_C     0.85096556f            // closed form of the MAX_ITERS recurrence

#if __has_builtin(__builtin_amdgcn_exp2f)
#define EXP2(x) __builtin_amdgcn_exp2f(x)   // raw v_exp_f32 (1 ulp), no libm fixups
#else
#define EXP2(x) exp2f(x)
#endif

typedef __attribute__((ext_vector_type(8))) short short8;
typedef __attribute__((ext_vector_type(4))) float f32x4;

__device__ __forceinline__ unsigned short f2bf(float x) {       // RNE (GEMM epilogues)
    union { float f; unsigned int u; } v; v.f = x;
    unsigned int r = (v.u + 0x7fffu + ((v.u >> 16) & 1u)) >> 16;
    return (unsigned short)r;
}
__device__ __forceinline__ unsigned short f2bf_fast(float x) {  // round-half-up, 2 ops
    union { float f; unsigned int u; } v; v.f = x;
    return (unsigned short)((v.u + 0x8000u) >> 16);
}
__device__ __forceinline__ float bf2f(unsigned short x) {
    union { unsigned int u; float f; } v; v.u = ((unsigned int)x) << 16;
    return v.f;
}
// packed f32x2 -> bf16x2 (no builtin on gfx950 — inline asm per guide m240)
__device__ __forceinline__ unsigned cvtpk_bf16(float lo, float hi) {
    unsigned r;
    asm("v_cvt_pk_bf16_f32 %0, %1, %2" : "=v"(r) : "v"(lo), "v"(hi));
    return r;
}

// async global->LDS, 16B per lane; LDS dest = wave-uniform base + lane*16 [m97]
__device__ __forceinline__ void glds16(const unsigned short* g, unsigned short* l) {
    __builtin_amdgcn_global_load_lds((const __attribute__((address_space(1))) unsigned int*)g,
                                     (__attribute__((address_space(3))) unsigned int*)l,
                                     16, 0, 0);
}

__global__ void zero_out_f32(float* p, int n) {
    int i = blockIdx.x * 256 + threadIdx.x;
    if (i < n) p[i] = 0.f;
}

// ---------------------------------------------------------------------------
// cvt5: fp32 -> bf16 for hs (4M elems) + qw/kw/vw/ow (1M each). Zeros entp.
// ---------------------------------------------------------------------------
__global__ __launch_bounds__(256) void cvt5(
    const float* __restrict__ s0, const float* __restrict__ s1, const float* __restrict__ s2,
    const float* __restrict__ s3, const float* __restrict__ s4,
    unsigned short* __restrict__ d0, unsigned short* __restrict__ d1, unsigned short* __restrict__ d2,
    unsigned short* __restrict__ d3, unsigned short* __restrict__ d4, float* entp)
{
    if (blockIdx.x == 0 && threadIdx.x == 0) entp[0] = 0.f;
    unsigned int i = blockIdx.x * 256 + threadIdx.x;   // float4 group index, total 2^21
    const float* s; unsigned short* d; unsigned int off;
    if (i < (1u << 20)) { s = s0; d = d0; off = i; }
    else {
        unsigned int j = i - (1u << 20);
        unsigned int sel = j >> 18; off = j & 0x3FFFFu;
        s = sel == 0 ? s1 : sel == 1 ? s2 : sel == 2 ? s3 : s4;
        d = sel == 0 ? d1 : sel == 1 ? d2 : sel == 2 ? d3 : d4;
    }
    float4 v = ((const float4*)s)[off];
    ushort4 p; p.x = f2bf(v.x); p.y = f2bf(v.y); p.z = f2bf(v.z); p.w = f2bf(v.w);
    ((ushort4*)d)[off] = p;
}

// ---------------------------------------------------------------------------
// gemm_qkv: R19 fused-QK + V. 512 blocks: x=bid&7 (XCD m-band), i=bid>>3;
// i<32 -> fused QK block (As shared, 32 MFMA / 2 barriers / K-step);
// i>=32 -> V block (unchanged structure).
// ---------------------------------------------------------------------------
__global__ __launch_bounds__(256, 2) void gemm_qkv(
    const unsigned short* __restrict__ hsb,
    const unsigned short* __restrict__ qwb, const unsigned short* __restrict__ kwb,
    const unsigned short* __restrict__ vwb,
    const float* __restrict__ qb, const float* __restrict__ kb, const float* __restrict__ vb,
    unsigned short* __restrict__ Qo, unsigned short* __restrict__ Ko, unsigned short* __restrict__ Vto)
{
    const int x = blockIdx.x & 7;       // XCD (HW round-robins bid%8)
    const int i = blockIdx.x >> 3;      // 0..63
    const bool isQK = (i < 32);
    const int j = isQK ? i : i - 32;    // 0..31

    __shared__ unsigned short As[128 * 32];
    __shared__ unsigned short B0s[128 * 32];
    __shared__ unsigned short B1s[128 * 32];   // QK only; 24KB total
    const int t = threadIdx.x, lane = t & 63, w = t >> 6;
    const int quad = lane >> 4, l15 = lane & 15;
    const int wr = (w >> 1) * 64, wc = (w & 1) * 64;
    const int srow = lane >> 2, scol = (lane & 3) * 8;

    const unsigned short *A, *B0;
    int m0, n0;
    if (isQK) {  // A = hs (m-band per XCD), B0 = qw, B1 = kw
        m0 = (x * 4 + (j >> 3)) * 128;  // 0..31 m-tiles (M=4096)
        n0 = (j & 7) * 128;             // 0..7 n-tiles (N=1024)
        A = hsb; B0 = qwb;
    } else {     // V: A = vw, B0 = hs (n-band per XCD), C = Vt (ldc 4096)
        m0 = (j & 7) * 128;
        n0 = (x * 4 + (j >> 3)) * 128;
        A = vwb; B0 = hsb;
    }

    f32x4 acc0[4][4], acc1[4][4];
#pragma unroll
    for (int ii = 0; ii < 4; ++ii)
#pragma unroll
        for (int jj = 0; jj < 4; ++jj) {
            acc0[ii][jj] = (f32x4){0.f, 0.f, 0.f, 0.f};
            acc1[ii][jj] = (f32x4){0.f, 0.f, 0.f, 0.f};
        }

    for (int kk = 0; kk < 32; ++kk) {
        const int k0 = kk * 32;
#pragma unroll
        for (int jj = 0; jj < 2; ++jj) {
            int row = (w * 2 + jj) * 16 + srow;
            glds16(&A[(size_t)(m0 + row) * 1024 + k0 + scol], &As[(w * 2 + jj) * 512]);
            glds16(&B0[(size_t)(n0 + row) * 1024 + k0 + scol], &B0s[(w * 2 + jj) * 512]);
            if (isQK)
                glds16(&kwb[(size_t)(n0 + row) * 1024 + k0 + scol], &B1s[(w * 2 + jj) * 512]);
        }
        __syncthreads();
        short8 af[4], bf0[4];
#pragma unroll
        for (int mt = 0; mt < 4; ++mt) af[mt] = *(const short8*)&As[(wr + mt * 16 + l15) * 32 + quad * 8];
#pragma unroll
        for (int nt = 0; nt < 4; ++nt) bf0[nt] = *(const short8*)&B0s[(wc + nt * 16 + l15) * 32 + quad * 8];
#pragma unroll
        for (int mt = 0; mt < 4; ++mt)
#pragma unroll
            for (int nt = 0; nt < 4; ++nt)
                acc0[mt][nt] = __builtin_amdgcn_mfma_f32_16x16x32_bf16(af[mt], bf0[nt], acc0[mt][nt], 0, 0, 0);
        if (isQK) {
            short8 bf1[4];
#pragma unroll
            for (int nt = 0; nt < 4; ++nt) bf1[nt] = *(const short8*)&B1s[(wc + nt * 16 + l15) * 32 + quad * 8];
#pragma unroll
            for (int mt = 0; mt < 4; ++mt)
#pragma unroll
                for (int nt = 0; nt < 4; ++nt)
                    acc1[mt][nt] = __builtin_amdgcn_mfma_f32_16x16x32_bf16(af[mt], bf1[nt], acc1[mt][nt], 0, 0, 0);
        }
        __syncthreads();
    }

    if (isQK) {
#pragma unroll
        for (int mt = 0; mt < 4; ++mt) {
#pragma unroll
            for (int nt = 0; nt < 4; ++nt) {
                int n = n0 + wc + nt * 16 + l15;
#pragma unroll
                for (int r = 0; r < 4; ++r) {
                    int m = m0 + wr + mt * 16 + quad * 4 + r;
                    Qo[(size_t)m * 1024 + n] = f2bf((acc0[mt][nt][r] + qb[n]) * QSCALE);
                    Ko[(size_t)m * 1024 + n] = f2bf(acc1[mt][nt][r] + kb[n]);
                }
            }
        }
    } else {
#pragma unroll
        for (int mt = 0; mt < 4; ++mt) {
#pragma unroll
            for (int nt = 0; nt < 4; ++nt) {
                int n = n0 + wc + nt * 16 + l15;
#pragma unroll
                for (int r = 0; r < 4; ++r) {
                    int m = m0 + wr + mt * 16 + quad * 4 + r;
                    Vto[(size_t)m * 4096 + n] = f2bf(acc0[mt][nt][r] + vb[m]);
                }
            }
        }
    }
}

// ---------------------------------------------------------------------------
// flash_full: full-k flash (32 k-tiles). 128-q blocks (st=2), grid 512 =
// 2 blk/CU. Epilogue: normalize O from fp32 accs (exact 1/l), per-row
// entropy reduced to ONE atomicAdd per block.
// ---------------------------------------------------------------------------

#define STAGE(KT, BUF) do {                                                         \
    int kn_ = (KT) * 64;                                                            \
    _Pragma("unroll")                                                               \
    for (int i_ = 0; i_ < 2; ++i_) {                                                \
        int row_ = w * 16 + i_ * 8 + r8;                                            \
        int c_ = ch8 ^ (row_ & 7);                                                  \
        glds16(&K[(size_t)(b * 2048 + kn_ + row_) * 1024 + h * 64 + c_ * 8],        \
               &Ks[BUF][(w * 16 + i_ * 8) * 64]);                                   \
        glds16(&Vt[(size_t)(h * 64 + row_) * 4096 + b * 2048 + kn_ + c_ * 8],       \
               &Vs[BUF][(w * 16 + i_ * 8) * 64]);                                   \
    }                                                                               \
} while (0)

// QK^T + softmax phase; MASKED is a compile-time 0/1 (tile-uniform branch).
#define QK_SOFTMAX(MASKED)                                                          \
    _Pragma("unroll")                                                               \
    for (int nt = 0; nt < 4; ++nt) {                                                \
        int krow = nt * 16 + l15;                                                   \
        short8 kf0 = *(const short8*)&Ks[cur][krow * 64 + ((quad ^ (krow & 7)) * 8)];       \
        short8 kf1 = *(const short8*)&Ks[cur][krow * 64 + (((quad + 4) ^ (krow & 7)) * 8)]; \
        f32x4 sv[2];                                                                \
        __builtin_amdgcn_s_setprio(1);                                              \
        _Pragma("unroll")                                                           \
        for (int st = 0; st < 2; ++st) {                                            \
            sv[st] = __builtin_amdgcn_mfma_f32_16x16x32_bf16(kf0, qa[st][0], (f32x4){0.f, 0.f, 0.f, 0.f}, 0, 0, 0); \
            sv[st] = __builtin_amdgcn_mfma_f32_16x16x32_bf16(kf1, qa[st][1], sv[st], 0, 0, 0); \
        }                                                                           \
        __builtin_amdgcn_s_setprio(0);                                              \
        unsigned mb = 0xFu;                                                         \
        if (MASKED) {                                                               \
            unsigned mw = (nt & 2) ? mwB : mwA;                                     \
            mb = (mw >> (((nt & 1) << 4) + (quad << 2))) & 0xFu;                    \
        }                                                                           \
        _Pragma("unroll")                                                           \
        for (int st = 0; st < 2; ++st) {                                            \
            float s0 = sv[st][0], s1 = sv[st][1], s2 = sv[st][2], s3 = sv[st][3];   \
            if (MASKED) {                                                           \
                s0 = (mb & 1u) ? s0 : -1.0e30f;                                     \
                s1 = (mb & 2u) ? s1 : -1.0e30f;                                     \
                s2 = (mb & 4u) ? s2 : -1.0e30f;                                     \
                s3 = (mb & 8u) ? s3 : -1.0e30f;                                     \
            }                                                                       \
            float p0 = EXP2(s0), p1 = EXP2(s1), p2 = EXP2(s2), p3 = EXP2(s3);       \
            l_r[st] += (p0 + p1) + (p2 + p3);                                       \
            T_r[st] += (p0 * s0 + p1 * s1) + (p2 * s2 + p3 * s3);                   \
            pk[nt][st][0] = cvtpk_bf16(p0, p1);                                     \
            pk[nt][st][1] = cvtpk_bf16(p2, p3);                                     \
        }                                                                           \
    }

__global__ __launch_bounds__(256, 2) void flash_full(
    const unsigned short* __restrict__ Q,
    const unsigned short* __restrict__ K,
    const unsigned short* __restrict__ Vt,
    const int* __restrict__ mask,
    unsigned short* __restrict__ O,
    float* __restrict__ entp)
{
    // XCD swizzle: ww = (bid&7)*64 + bid>>3. All 16 qt of a bh on one XCD;
    // 4 bh/XCD -> K/V footprint 2MB < 4MB L2.
    const int ww = ((blockIdx.x & 7) << 6) + (blockIdx.x >> 3);
    const int qt = ww & 15;             // 0..15, 128 q-rows each
    const int bh = ww >> 4;             // 0..31
    const int b = bh >> 4, h = bh & 15;
    const int t = threadIdx.x, lane = t & 63, w = t >> 6;
    const int quad = lane >> 4, l15 = lane & 15;
    const int r8 = lane >> 3, ch8 = lane & 7;

    __shared__ __align__(16) unsigned short Ks[2][64 * 64];
    __shared__ __align__(16) unsigned short Vs[2][64 * 64];
    __shared__ unsigned int maskBits[64];        // 32 tiles x 2 words
    __shared__ float went[4];

    // Q fragments straight from global (16B per lane, once). Issued FIRST so
    // the in-loop vmcnt stream counts only glds16 (4/tile).
    short8 qa[2][2];
#pragma unroll
    for (int st = 0; st < 2; ++st) {
        size_t qrow = (size_t)(b * 2048 + qt * 128 + w * 32 + st * 16 + l15) * 1024 + h * 64;
        union { uint4 v; short8 s8; } u0, u1;
        u0.v = *(const uint4*)&Q[qrow + quad * 8];
        u1.v = *(const uint4*)&Q[qrow + 32 + quad * 8];
        qa[st][0] = u0.s8; qa[st][1] = u1.s8;
    }

    {   // bit-pack whole mask row (thread t packs 8 ints -> 1 byte), all 32 tiles
        const int4* mp = (const int4*)(mask + b * 2048 + t * 8);
        int4 a = mp[0], c = mp[1];
        unsigned bits = (unsigned)(a.x != 0)       | ((unsigned)(a.y != 0) << 1)
                      | ((unsigned)(a.z != 0) << 2) | ((unsigned)(a.w != 0) << 3)
                      | ((unsigned)(c.x != 0) << 4) | ((unsigned)(c.y != 0) << 5)
                      | ((unsigned)(c.z != 0) << 6) | ((unsigned)(c.w != 0) << 7);
        ((unsigned char*)maskBits)[t] = (unsigned char)bits;
    }

    STAGE(0, 0);
    STAGE(1, 1);

    float l_r[2] = {0.f, 0.f}, T_r[2] = {0.f, 0.f};
    f32x4 o_acc[2][4];
#pragma unroll
    for (int st = 0; st < 2; ++st)
#pragma unroll
        for (int nt = 0; nt < 4; ++nt) o_acc[st][nt] = (f32x4){0.f, 0.f, 0.f, 0.f};

    // prologue sync: maskBits visible (lgkm) + tile 0 staged (4 younger = tile 1)
    asm volatile("s_waitcnt lgkmcnt(0)" ::: "memory");
    asm volatile("s_waitcnt vmcnt(4)" ::: "memory");
    asm volatile("s_barrier" ::: "memory");

    for (int kt = 0; kt < 32; ++kt) {
        const int cur = kt & 1;
        unsigned mwA = maskBits[kt * 2], mwB = maskBits[kt * 2 + 1];

        // QK^T + softmax -> pk[nt][st][h] (P^T k-pair u32s, in registers)
        unsigned pk[4][2][2];
        if ((mwA & mwB) == 0xFFFFFFFFu) {
            QK_SOFTMAX(0)
        } else {
            QK_SOFTMAX(1)
        }

        // PV: redistribute P^T -> PV A-frags in-register, then O += P*V.
#pragma unroll
        for (int ks = 0; ks < 2; ++ks) {
            short8 pa[2];
#pragma unroll
            for (int st = 0; st < 2; ++st) {
                unsigned a0 = pk[2 * ks][st][0], a1 = pk[2 * ks][st][1];
                unsigned b0 = pk[2 * ks + 1][st][0], b1 = pk[2 * ks + 1][st][1];
                asm("v_permlane32_swap_b32 %0, %1" : "+v"(a0), "+v"(b0));
                asm("v_permlane32_swap_b32 %0, %1" : "+v"(a1), "+v"(b1));
                asm("v_permlane16_swap_b32 %0, %1" : "+v"(a0), "+v"(b0));
                asm("v_permlane16_swap_b32 %0, %1" : "+v"(a1), "+v"(b1));
                union { unsigned u[4]; short8 s8; } uu;
                uu.u[0] = a0; uu.u[1] = a1; uu.u[2] = b0; uu.u[3] = b1;
                pa[st] = uu.s8;
            }
            __builtin_amdgcn_s_setprio(1);
#pragma unroll
            for (int nt = 0; nt < 4; ++nt) {
                int vrow = nt * 16 + l15;
                short8 vf = *(const short8*)&Vs[cur][vrow * 64 + ((((ks * 4 + quad)) ^ (vrow & 7)) * 8)];
#pragma unroll
                for (int st = 0; st < 2; ++st)
                    o_acc[st][nt] = __builtin_amdgcn_mfma_f32_16x16x32_bf16(pa[st], vf, o_acc[st][nt], 0, 0, 0);
            }
            __builtin_amdgcn_s_setprio(0);
        }

        // counted-vmcnt pipeline handoff (no vmcnt(0) in steady state)
        if (kt < 31) {
            asm volatile("s_barrier" ::: "memory");        // all waves done reading buf[cur]
            if (kt < 30) {
                STAGE(kt + 2, cur);                         // overwrite just-read buffer
                asm volatile("s_waitcnt vmcnt(4)" ::: "memory");   // kt+1's 4 loads retired
            } else {
                asm volatile("s_waitcnt vmcnt(0)" ::: "memory");   // tail: tile 31's loads
            }
            asm volatile("s_barrier" ::: "memory");        // staging visible to all waves
        }
    }

    // ---- epilogue: normalize O (exact 1/l on fp32 accs), entropy in-kernel ----
    float ent_acc = 0.f;
#pragma unroll
    for (int st = 0; st < 2; ++st) {
        float l = l_r[st], T = T_r[st];
        l += __shfl_xor(l, 16); T += __shfl_xor(T, 16);
        l += __shfl_xor(l, 32); T += __shfl_xor(T, 32);
        // every lane now holds full l,T for q-row (st*16 + l15)
        ent_acc += __log2f(l) - T / l;
        float inv[4];
#pragma unroll
        for (int r = 0; r < 4; ++r)
            inv[r] = 1.0f / __shfl(l, quad * 4 + r);   // l of row quad*4+r
#pragma unroll
        for (int r = 0; r < 4; ++r) {
            int mrow = b * 2048 + qt * 128 + w * 32 + st * 16 + quad * 4 + r;
#pragma unroll
            for (int nt = 0; nt < 4; ++nt)
                O[(size_t)mrow * 1024 + h * 64 + nt * 16 + l15] = f2bf_fast(o_acc[st][nt][r] * inv[r]);
        }
    }
    // ent_acc: rows st*16+l15 summed over st; identical across quads. Reduce
    // over l15 -> sum of this wave's 32 rows; 1 atomic per block.
    ent_acc += __shfl_xor(ent_acc, 1);
    ent_acc += __shfl_xor(ent_acc, 2);
    ent_acc += __shfl_xor(ent_acc, 4);
    ent_acc += __shfl_xor(ent_acc, 8);
    if (lane == 0) went[w] = ent_acc;
    __syncthreads();
    if (t == 0)
        atomicAdd(entp, LN2 * (went[0] + went[1] + went[2] + went[3]));
}

// ---------------------------------------------------------------------------
// Output GEMM bf16: out = scale_ent * (O @ ow.T) + ob, fp32 out.
// 1D grid 256, XCD-partitioned (m-band per XCD: O-panel 1MB + ow 2MB).
// ---------------------------------------------------------------------------
__global__ __launch_bounds__(256) void gemm_out_bf(
    const unsigned short* __restrict__ A, const unsigned short* __restrict__ Bw,
    const float* __restrict__ bias, const float* __restrict__ entp,
    float* __restrict__ C)
{
    const float avg = entp[0] * (1.0f / 65536.0f);
    const float scale = (avg < 0.2f) ? 1.0f : BLEND_C;

    const int x = blockIdx.x & 7;       // XCD
    const int j = blockIdx.x >> 3;      // 0..31
    const int m0 = (x * 4 + (j >> 3)) * 128;
    const int n0 = (j & 7) * 128;
    __shared__ unsigned short As[128 * 32];
    __shared__ unsigned short Bs[128 * 32];
    const int t = threadIdx.x, lane = t & 63, w = t >> 6;
    const int quad = lane >> 4, l15 = lane & 15;
    const int wr = (w >> 1) * 64, wc = (w & 1) * 64;
    const int srow = lane >> 2, scol = (lane & 3) * 8;

    f32x4 acc[4][4];
#pragma unroll
    for (int ii = 0; ii < 4; ++ii)
#pragma unroll
        for (int jj = 0; jj < 4; ++jj) acc[ii][jj] = (f32x4){0.f, 0.f, 0.f, 0.f};

    for (int kk = 0; kk < 32; ++kk) {
        const int k0 = kk * 32;
#pragma unroll
        for (int jj = 0; jj < 2; ++jj) {
            int row = (w * 2 + jj) * 16 + srow;
            glds16(&A[(size_t)(m0 + row) * 1024 + k0 + scol], &As[(w * 2 + jj) * 512]);
            glds16(&Bw[(size_t)(n0 + row) * 1024 + k0 + scol], &Bs[(w * 2 + jj) * 512]);
        }
        __syncthreads();
        short8 af[4], bf[4];
#pragma unroll
        for (int mt = 0; mt < 4; ++mt) af[mt] = *(const short8*)&As[(wr + mt * 16 + l15) * 32 + quad * 8];
#pragma unroll
        for (int nt = 0; nt < 4; ++nt) bf[nt] = *(const short8*)&Bs[(wc + nt * 16 + l15) * 32 + quad * 8];
#pragma unroll
        for (int mt = 0; mt < 4; ++mt)
#pragma unroll
            for (int nt = 0; nt < 4; ++nt)
                acc[mt][nt] = __builtin_amdgcn_mfma_f32_16x16x32_bf16(af[mt], bf[nt], acc[mt][nt], 0, 0, 0);
        __syncthreads();
    }
#pragma unroll
    for (int mt = 0; mt < 4; ++mt) {
#pragma unroll
        for (int nt = 0; nt < 4; ++nt) {
            int n = n0 + wc + nt * 16 + l15;
#pragma unroll
            for (int r = 0; r < 4; ++r) {
                int m = m0 + wr + mt * 16 + quad * 4 + r;
                C[(size_t)m * 1024 + n] = scale * acc[mt][nt][r] + bias[n];
            }
        }
    }
}

extern "C" void kernel_launch(void* const* d_in, const int* in_sizes, int n_in,
                              void* d_out, int out_size, void* d_ws, size_t ws_size,
                              hipStream_t stream)
{
    const float* hs = (const float*)d_in[0];
    const float* qw = (const float*)d_in[1];
    const float* qb = (const float*)d_in[2];
    const float* kw = (const float*)d_in[3];
    const float* kb = (const float*)d_in[4];
    const float* vw = (const float*)d_in[5];
    const float* vb = (const float*)d_in[6];
    const float* ow = (const float*)d_in[7];
    const float* ob = (const float*)d_in[8];
    const int*   mask = (const int*)d_in[9];
    float* out = (float*)d_out;

    const size_t MB = 1024 * 1024;
    char* ws = (char*)d_ws;
    dim3 blk(256);

    if (ws_size >= 50 * MB) {
        unsigned short* hsb = (unsigned short*)(ws);            // 8MB; later final O
        unsigned short* Q   = (unsigned short*)(ws + 8 * MB);
        unsigned short* Kp  = (unsigned short*)(ws + 16 * MB);
        unsigned short* Vt  = (unsigned short*)(ws + 24 * MB);
        unsigned short* qwb = (unsigned short*)(ws + 32 * MB);
        unsigned short* kwb = (unsigned short*)(ws + 34 * MB);
        unsigned short* vwb = (unsigned short*)(ws + 36 * MB);
        unsigned short* owb = (unsigned short*)(ws + 38 * MB);
        float* entp         = (float*)(ws + 40 * MB);
        unsigned short* O   = hsb;                              // normalized O (in-place over hsb)

        cvt5<<<dim3(8192), blk, 0, stream>>>(hs, qw, kw, vw, ow, hsb, qwb, kwb, vwb, owb, entp);
        gemm_qkv<<<dim3(512), blk, 0, stream>>>(hsb, qwb, kwb, vwb, qb, kb, vb, Q, Kp, Vt);
        flash_full<<<dim3(512), blk, 0, stream>>>(Q, Kp, Vt, mask, O, entp);
        gemm_out_bf<<<dim3(256), blk, 0, stream>>>(O, owb, ob, entp, out);
    } else {
        // diagnostic: clean zero output instead of OOB fault
        zero_out_f32<<<dim3((out_size + 255) / 256), blk, 0, stream>>>(out, out_size);
    }
}

// Round 11
// 209.511 us; speedup vs baseline: 1.0023x; 1.0023x over previous
//
#include <hip/hip_runtime.h>
#include <hip/hip_bf16.h>
#include <stdint.h>

// ResonanceAttention on MI355X (gfx950) — round 20.
// R19 post-mortem: fused-QK regressed +6us NOT from the fusion (absmax
// identical) but from block->CU packing: all QK blocks in the first half of
// each XCD's sequence -> CUs got (QK,QK)=4T or (V,V)=2T -> 2x makespan.
// R20: identical fused kernel, op chosen by PARITY of the per-XCD sequence
// index (s&1): consecutive per-XCD blocks = (QK,V) -> every CU balanced at
// 3T. Fusion savings (A staged once: 6 vs 8 glds/step; half the barrier
// windows; V block fills QK drain windows) can now show.
// Pipeline: cvt5 -> gemm_qkv(fused QK + V) -> flash_full -> gemm_out_bf.

#define PRIME_SCALE 0.047245559126654356f  // 1/sqrt(7*64)
#define LOG2E       1.4426950408889634f
#define LN2         0.6931471805599453f
#define QSCALE      (PRIME_SCALE * LOG2E)  // Q pre-scaled so softmax uses exp2
#define BLEND_C     0.85096556f            // closed form of the MAX_ITERS recurrence

#if __has_builtin(__builtin_amdgcn_exp2f)
#define EXP2(x) __builtin_amdgcn_exp2f(x)   // raw v_exp_f32 (1 ulp), no libm fixups
#else
#define EXP2(x) exp2f(x)
#endif

typedef __attribute__((ext_vector_type(8))) short short8;
typedef __attribute__((ext_vector_type(4))) float f32x4;

__device__ __forceinline__ unsigned short f2bf(float x) {       // RNE (GEMM epilogues)
    union { float f; unsigned int u; } v; v.f = x;
    unsigned int r = (v.u + 0x7fffu + ((v.u >> 16) & 1u)) >> 16;
    return (unsigned short)r;
}
__device__ __forceinline__ unsigned short f2bf_fast(float x) {  // round-half-up, 2 ops
    union { float f; unsigned int u; } v; v.f = x;
    return (unsigned short)((v.u + 0x8000u) >> 16);
}
__device__ __forceinline__ float bf2f(unsigned short x) {
    union { unsigned int u; float f; } v; v.u = ((unsigned int)x) << 16;
    return v.f;
}
// packed f32x2 -> bf16x2 (no builtin on gfx950 — inline asm per guide m240)
__device__ __forceinline__ unsigned cvtpk_bf16(float lo, float hi) {
    unsigned r;
    asm("v_cvt_pk_bf16_f32 %0, %1, %2" : "=v"(r) : "v"(lo), "v"(hi));
    return r;
}

// async global->LDS, 16B per lane; LDS dest = wave-uniform base + lane*16 [m97]
__device__ __forceinline__ void glds16(const unsigned short* g, unsigned short* l) {
    __builtin_amdgcn_global_load_lds((const __attribute__((address_space(1))) unsigned int*)g,
                                     (__attribute__((address_space(3))) unsigned int*)l,
                                     16, 0, 0);
}

__global__ void zero_out_f32(float* p, int n) {
    int i = blockIdx.x * 256 + threadIdx.x;
    if (i < n) p[i] = 0.f;
}

// ---------------------------------------------------------------------------
// cvt5: fp32 -> bf16 for hs (4M elems) + qw/kw/vw/ow (1M each). Zeros entp.
// ---------------------------------------------------------------------------
__global__ __launch_bounds__(256) void cvt5(
    const float* __restrict__ s0, const float* __restrict__ s1, const float* __restrict__ s2,
    const float* __restrict__ s3, const float* __restrict__ s4,
    unsigned short* __restrict__ d0, unsigned short* __restrict__ d1, unsigned short* __restrict__ d2,
    unsigned short* __restrict__ d3, unsigned short* __restrict__ d4, float* entp)
{
    if (blockIdx.x == 0 && threadIdx.x == 0) entp[0] = 0.f;
    unsigned int i = blockIdx.x * 256 + threadIdx.x;   // float4 group index, total 2^21
    const float* s; unsigned short* d; unsigned int off;
    if (i < (1u << 20)) { s = s0; d = d0; off = i; }
    else {
        unsigned int j = i - (1u << 20);
        unsigned int sel = j >> 18; off = j & 0x3FFFFu;
        s = sel == 0 ? s1 : sel == 1 ? s2 : sel == 2 ? s3 : s4;
        d = sel == 0 ? d1 : sel == 1 ? d2 : sel == 2 ? d3 : d4;
    }
    float4 v = ((const float4*)s)[off];
    ushort4 p; p.x = f2bf(v.x); p.y = f2bf(v.y); p.z = f2bf(v.z); p.w = f2bf(v.w);
    ((ushort4*)d)[off] = p;
}

// ---------------------------------------------------------------------------
// gemm_qkv: fused QK + V. 512 blocks: x=bid&7 (XCD), s=bid>>3 (per-XCD seq).
// op = s&1 (R20 parity fix): consecutive per-XCD blocks = (QK, V) -> every
// CU gets one of each. QK block: As shared, 32 MFMA / 2 barriers / K-step.
// ---------------------------------------------------------------------------
__global__ __launch_bounds__(256, 2) void gemm_qkv(
    const unsigned short* __restrict__ hsb,
    const unsigned short* __restrict__ qwb, const unsigned short* __restrict__ kwb,
    const unsigned short* __restrict__ vwb,
    const float* __restrict__ qb, const float* __restrict__ kb, const float* __restrict__ vb,
    unsigned short* __restrict__ Qo, unsigned short* __restrict__ Ko, unsigned short* __restrict__ Vto)
{
    const int x = blockIdx.x & 7;       // XCD (HW round-robins bid%8)
    const int s = blockIdx.x >> 3;      // 0..63, per-XCD dispatch sequence
    const bool isQK = (s & 1) == 0;     // parity interleave: (QK,V) pairs per CU
    const int j = s >> 1;               // 0..31

    __shared__ unsigned short As[128 * 32];
    __shared__ unsigned short B0s[128 * 32];
    __shared__ unsigned short B1s[128 * 32];   // QK only; 24KB total
    const int t = threadIdx.x, lane = t & 63, w = t >> 6;
    const int quad = lane >> 4, l15 = lane & 15;
    const int wr = (w >> 1) * 64, wc = (w & 1) * 64;
    const int srow = lane >> 2, scol = (lane & 3) * 8;

    const unsigned short *A, *B0;
    int m0, n0;
    if (isQK) {  // A = hs (m-band per XCD), B0 = qw, B1 = kw
        m0 = (x * 4 + (j >> 3)) * 128;  // 0..31 m-tiles (M=4096)
        n0 = (j & 7) * 128;             // 0..7 n-tiles (N=1024)
        A = hsb; B0 = qwb;
    } else {     // V: A = vw, B0 = hs (n-band per XCD), C = Vt (ldc 4096)
        m0 = (j & 7) * 128;
        n0 = (x * 4 + (j >> 3)) * 128;
        A = vwb; B0 = hsb;
    }

    f32x4 acc0[4][4], acc1[4][4];
#pragma unroll
    for (int ii = 0; ii < 4; ++ii)
#pragma unroll
        for (int jj = 0; jj < 4; ++jj) {
            acc0[ii][jj] = (f32x4){0.f, 0.f, 0.f, 0.f};
            acc1[ii][jj] = (f32x4){0.f, 0.f, 0.f, 0.f};
        }

    for (int kk = 0; kk < 32; ++kk) {
        const int k0 = kk * 32;
#pragma unroll
        for (int jj = 0; jj < 2; ++jj) {
            int row = (w * 2 + jj) * 16 + srow;
            glds16(&A[(size_t)(m0 + row) * 1024 + k0 + scol], &As[(w * 2 + jj) * 512]);
            glds16(&B0[(size_t)(n0 + row) * 1024 + k0 + scol], &B0s[(w * 2 + jj) * 512]);
            if (isQK)
                glds16(&kwb[(size_t)(n0 + row) * 1024 + k0 + scol], &B1s[(w * 2 + jj) * 512]);
        }
        __syncthreads();
        short8 af[4], bf0[4];
#pragma unroll
        for (int mt = 0; mt < 4; ++mt) af[mt] = *(const short8*)&As[(wr + mt * 16 + l15) * 32 + quad * 8];
#pragma unroll
        for (int nt = 0; nt < 4; ++nt) bf0[nt] = *(const short8*)&B0s[(wc + nt * 16 + l15) * 32 + quad * 8];
#pragma unroll
        for (int mt = 0; mt < 4; ++mt)
#pragma unroll
            for (int nt = 0; nt < 4; ++nt)
                acc0[mt][nt] = __builtin_amdgcn_mfma_f32_16x16x32_bf16(af[mt], bf0[nt], acc0[mt][nt], 0, 0, 0);
        if (isQK) {
            short8 bf1[4];
#pragma unroll
            for (int nt = 0; nt < 4; ++nt) bf1[nt] = *(const short8*)&B1s[(wc + nt * 16 + l15) * 32 + quad * 8];
#pragma unroll
            for (int mt = 0; mt < 4; ++mt)
#pragma unroll
                for (int nt = 0; nt < 4; ++nt)
                    acc1[mt][nt] = __builtin_amdgcn_mfma_f32_16x16x32_bf16(af[mt], bf1[nt], acc1[mt][nt], 0, 0, 0);
        }
        __syncthreads();
    }

    if (isQK) {
#pragma unroll
        for (int mt = 0; mt < 4; ++mt) {
#pragma unroll
            for (int nt = 0; nt < 4; ++nt) {
                int n = n0 + wc + nt * 16 + l15;
#pragma unroll
                for (int r = 0; r < 4; ++r) {
                    int m = m0 + wr + mt * 16 + quad * 4 + r;
                    Qo[(size_t)m * 1024 + n] = f2bf((acc0[mt][nt][r] + qb[n]) * QSCALE);
                    Ko[(size_t)m * 1024 + n] = f2bf(acc1[mt][nt][r] + kb[n]);
                }
            }
        }
    } else {
#pragma unroll
        for (int mt = 0; mt < 4; ++mt) {
#pragma unroll
            for (int nt = 0; nt < 4; ++nt) {
                int n = n0 + wc + nt * 16 + l15;
#pragma unroll
                for (int r = 0; r < 4; ++r) {
                    int m = m0 + wr + mt * 16 + quad * 4 + r;
                    Vto[(size_t)m * 4096 + n] = f2bf(acc0[mt][nt][r] + vb[m]);
                }
            }
        }
    }
}

// ---------------------------------------------------------------------------
// flash_full: full-k flash (32 k-tiles). 128-q blocks (st=2), grid 512 =
// 2 blk/CU. Epilogue: normalize O from fp32 accs (exact 1/l), per-row
// entropy reduced to ONE atomicAdd per block.
// ---------------------------------------------------------------------------

#define STAGE(KT, BUF) do {                                                         \
    int kn_ = (KT) * 64;                                                            \
    _Pragma("unroll")                                                               \
    for (int i_ = 0; i_ < 2; ++i_) {                                                \
        int row_ = w * 16 + i_ * 8 + r8;                                            \
        int c_ = ch8 ^ (row_ & 7);                                                  \
        glds16(&K[(size_t)(b * 2048 + kn_ + row_) * 1024 + h * 64 + c_ * 8],        \
               &Ks[BUF][(w * 16 + i_ * 8) * 64]);                                   \
        glds16(&Vt[(size_t)(h * 64 + row_) * 4096 + b * 2048 + kn_ + c_ * 8],       \
               &Vs[BUF][(w * 16 + i_ * 8) * 64]);                                   \
    }                                                                               \
} while (0)

// QK^T + softmax phase; MASKED is a compile-time 0/1 (tile-uniform branch).
#define QK_SOFTMAX(MASKED)                                                          \
    _Pragma("unroll")                                                               \
    for (int nt = 0; nt < 4; ++nt) {                                                \
        int krow = nt * 16 + l15;                                                   \
        short8 kf0 = *(const short8*)&Ks[cur][krow * 64 + ((quad ^ (krow & 7)) * 8)];       \
        short8 kf1 = *(const short8*)&Ks[cur][krow * 64 + (((quad + 4) ^ (krow & 7)) * 8)]; \
        f32x4 sv[2];                                                                \
        __builtin_amdgcn_s_setprio(1);                                              \
        _Pragma("unroll")                                                           \
        for (int st = 0; st < 2; ++st) {                                            \
            sv[st] = __builtin_amdgcn_mfma_f32_16x16x32_bf16(kf0, qa[st][0], (f32x4){0.f, 0.f, 0.f, 0.f}, 0, 0, 0); \
            sv[st] = __builtin_amdgcn_mfma_f32_16x16x32_bf16(kf1, qa[st][1], sv[st], 0, 0, 0); \
        }                                                                           \
        __builtin_amdgcn_s_setprio(0);                                              \
        unsigned mb = 0xFu;                                                         \
        if (MASKED) {                                                               \
            unsigned mw = (nt & 2) ? mwB : mwA;                                     \
            mb = (mw >> (((nt & 1) << 4) + (quad << 2))) & 0xFu;                    \
        }                                                                           \
        _Pragma("unroll")                                                           \
        for (int st = 0; st < 2; ++st) {                                            \
            float s0 = sv[st][0], s1 = sv[st][1], s2 = sv[st][2], s3 = sv[st][3];   \
            if (MASKED) {                                                           \
                s0 = (mb & 1u) ? s0 : -1.0e30f;                                     \
                s1 = (mb & 2u) ? s1 : -1.0e30f;                                     \
                s2 = (mb & 4u) ? s2 : -1.0e30f;                                     \
                s3 = (mb & 8u) ? s3 : -1.0e30f;                                     \
            }                                                                       \
            float p0 = EXP2(s0), p1 = EXP2(s1), p2 = EXP2(s2), p3 = EXP2(s3);       \
            l_r[st] += (p0 + p1) + (p2 + p3);                                       \
            T_r[st] += (p0 * s0 + p1 * s1) + (p2 * s2 + p3 * s3);                   \
            pk[nt][st][0] = cvtpk_bf16(p0, p1);                                     \
            pk[nt][st][1] = cvtpk_bf16(p2, p3);                                     \
        }                                                                           \
    }

__global__ __launch_bounds__(256, 2) void flash_full(
    const unsigned short* __restrict__ Q,
    const unsigned short* __restrict__ K,
    const unsigned short* __restrict__ Vt,
    const int* __restrict__ mask,
    unsigned short* __restrict__ O,
    float* __restrict__ entp)
{
    // XCD swizzle: ww = (bid&7)*64 + bid>>3. All 16 qt of a bh on one XCD;
    // 4 bh/XCD -> K/V footprint 2MB < 4MB L2.
    const int ww = ((blockIdx.x & 7) << 6) + (blockIdx.x >> 3);
    const int qt = ww & 15;             // 0..15, 128 q-rows each
    const int bh = ww >> 4;             // 0..31
    const int b = bh >> 4, h = bh & 15;
    const int t = threadIdx.x, lane = t & 63, w = t >> 6;
    const int quad = lane >> 4, l15 = lane & 15;
    const int r8 = lane >> 3, ch8 = lane & 7;

    __shared__ __align__(16) unsigned short Ks[2][64 * 64];
    __shared__ __align__(16) unsigned short Vs[2][64 * 64];
    __shared__ unsigned int maskBits[64];        // 32 tiles x 2 words
    __shared__ float went[4];

    // Q fragments straight from global (16B per lane, once). Issued FIRST so
    // the in-loop vmcnt stream counts only glds16 (4/tile).
    short8 qa[2][2];
#pragma unroll
    for (int st = 0; st < 2; ++st) {
        size_t qrow = (size_t)(b * 2048 + qt * 128 + w * 32 + st * 16 + l15) * 1024 + h * 64;
        union { uint4 v; short8 s8; } u0, u1;
        u0.v = *(const uint4*)&Q[qrow + quad * 8];
        u1.v = *(const uint4*)&Q[qrow + 32 + quad * 8];
        qa[st][0] = u0.s8; qa[st][1] = u1.s8;
    }

    {   // bit-pack whole mask row (thread t packs 8 ints -> 1 byte), all 32 tiles
        const int4* mp = (const int4*)(mask + b * 2048 + t * 8);
        int4 a = mp[0], c = mp[1];
        unsigned bits = (unsigned)(a.x != 0)       | ((unsigned)(a.y != 0) << 1)
                      | ((unsigned)(a.z != 0) << 2) | ((unsigned)(a.w != 0) << 3)
                      | ((unsigned)(c.x != 0) << 4) | ((unsigned)(c.y != 0) << 5)
                      | ((unsigned)(c.z != 0) << 6) | ((unsigned)(c.w != 0) << 7);
        ((unsigned char*)maskBits)[t] = (unsigned char)bits;
    }

    STAGE(0, 0);
    STAGE(1, 1);

    float l_r[2] = {0.f, 0.f}, T_r[2] = {0.f, 0.f};
    f32x4 o_acc[2][4];
#pragma unroll
    for (int st = 0; st < 2; ++st)
#pragma unroll
        for (int nt = 0; nt < 4; ++nt) o_acc[st][nt] = (f32x4){0.f, 0.f, 0.f, 0.f};

    // prologue sync: maskBits visible (lgkm) + tile 0 staged (4 younger = tile 1)
    asm volatile("s_waitcnt lgkmcnt(0)" ::: "memory");
    asm volatile("s_waitcnt vmcnt(4)" ::: "memory");
    asm volatile("s_barrier" ::: "memory");

    for (int kt = 0; kt < 32; ++kt) {
        const int cur = kt & 1;
        unsigned mwA = maskBits[kt * 2], mwB = maskBits[kt * 2 + 1];

        // QK^T + softmax -> pk[nt][st][h] (P^T k-pair u32s, in registers)
        unsigned pk[4][2][2];
        if ((mwA & mwB) == 0xFFFFFFFFu) {
            QK_SOFTMAX(0)
        } else {
            QK_SOFTMAX(1)
        }

        // PV: redistribute P^T -> PV A-frags in-register, then O += P*V.
#pragma unroll
        for (int ks = 0; ks < 2; ++ks) {
            short8 pa[2];
#pragma unroll
            for (int st = 0; st < 2; ++st) {
                unsigned a0 = pk[2 * ks][st][0], a1 = pk[2 * ks][st][1];
                unsigned b0 = pk[2 * ks + 1][st][0], b1 = pk[2 * ks + 1][st][1];
                asm("v_permlane32_swap_b32 %0, %1" : "+v"(a0), "+v"(b0));
                asm("v_permlane32_swap_b32 %0, %1" : "+v"(a1), "+v"(b1));
                asm("v_permlane16_swap_b32 %0, %1" : "+v"(a0), "+v"(b0));
                asm("v_permlane16_swap_b32 %0, %1" : "+v"(a1), "+v"(b1));
                union { unsigned u[4]; short8 s8; } uu;
                uu.u[0] = a0; uu.u[1] = a1; uu.u[2] = b0; uu.u[3] = b1;
                pa[st] = uu.s8;
            }
            __builtin_amdgcn_s_setprio(1);
#pragma unroll
            for (int nt = 0; nt < 4; ++nt) {
                int vrow = nt * 16 + l15;
                short8 vf = *(const short8*)&Vs[cur][vrow * 64 + ((((ks * 4 + quad)) ^ (vrow & 7)) * 8)];
#pragma unroll
                for (int st = 0; st < 2; ++st)
                    o_acc[st][nt] = __builtin_amdgcn_mfma_f32_16x16x32_bf16(pa[st], vf, o_acc[st][nt], 0, 0, 0);
            }
            __builtin_amdgcn_s_setprio(0);
        }

        // counted-vmcnt pipeline handoff (no vmcnt(0) in steady state)
        if (kt < 31) {
            asm volatile("s_barrier" ::: "memory");        // all waves done reading buf[cur]
            if (kt < 30) {
                STAGE(kt + 2, cur);                         // overwrite just-read buffer
                asm volatile("s_waitcnt vmcnt(4)" ::: "memory");   // kt+1's 4 loads retired
            } else {
                asm volatile("s_waitcnt vmcnt(0)" ::: "memory");   // tail: tile 31's loads
            }
            asm volatile("s_barrier" ::: "memory");        // staging visible to all waves
        }
    }

    // ---- epilogue: normalize O (exact 1/l on fp32 accs), entropy in-kernel ----
    float ent_acc = 0.f;
#pragma unroll
    for (int st = 0; st < 2; ++st) {
        float l = l_r[st], T = T_r[st];
        l += __shfl_xor(l, 16); T += __shfl_xor(T, 16);
        l += __shfl_xor(l, 32); T += __shfl_xor(T, 32);
        // every lane now holds full l,T for q-row (st*16 + l15)
        ent_acc += __log2f(l) - T / l;
        float inv[4];
#pragma unroll
        for (int r = 0; r < 4; ++r)
            inv[r] = 1.0f / __shfl(l, quad * 4 + r);   // l of row quad*4+r
#pragma unroll
        for (int r = 0; r < 4; ++r) {
            int mrow = b * 2048 + qt * 128 + w * 32 + st * 16 + quad * 4 + r;
#pragma unroll
            for (int nt = 0; nt < 4; ++nt)
                O[(size_t)mrow * 1024 + h * 64 + nt * 16 + l15] = f2bf_fast(o_acc[st][nt][r] * inv[r]);
        }
    }
    // ent_acc: rows st*16+l15 summed over st; identical across quads. Reduce
    // over l15 -> sum of this wave's 32 rows; 1 atomic per block.
    ent_acc += __shfl_xor(ent_acc, 1);
    ent_acc += __shfl_xor(ent_acc, 2);
    ent_acc += __shfl_xor(ent_acc, 4);
    ent_acc += __shfl_xor(ent_acc, 8);
    if (lane == 0) went[w] = ent_acc;
    __syncthreads();
    if (t == 0)
        atomicAdd(entp, LN2 * (went[0] + went[1] + went[2] + went[3]));
}

// ---------------------------------------------------------------------------
// Output GEMM bf16: out = scale_ent * (O @ ow.T) + ob, fp32 out.
// 1D grid 256, XCD-partitioned (m-band per XCD: O-panel 1MB + ow 2MB).
// ---------------------------------------------------------------------------
__global__ __launch_bounds__(256) void gemm_out_bf(
    const unsigned short* __restrict__ A, const unsigned short* __restrict__ Bw,
    const float* __restrict__ bias, const float* __restrict__ entp,
    float* __restrict__ C)
{
    const float avg = entp[0] * (1.0f / 65536.0f);
    const float scale = (avg < 0.2f) ? 1.0f : BLEND_C;

    const int x = blockIdx.x & 7;       // XCD
    const int j = blockIdx.x >> 3;      // 0..31
    const int m0 = (x * 4 + (j >> 3)) * 128;
    const int n0 = (j & 7) * 128;
    __shared__ unsigned short As[128 * 32];
    __shared__ unsigned short Bs[128 * 32];
    const int t = threadIdx.x, lane = t & 63, w = t >> 6;
    const int quad = lane >> 4, l15 = lane & 15;
    const int wr = (w >> 1) * 64, wc = (w & 1) * 64;
    const int srow = lane >> 2, scol = (lane & 3) * 8;

    f32x4 acc[4][4];
#pragma unroll
    for (int ii = 0; ii < 4; ++ii)
#pragma unroll
        for (int jj = 0; jj < 4; ++jj) acc[ii][jj] = (f32x4){0.f, 0.f, 0.f, 0.f};

    for (int kk = 0; kk < 32; ++kk) {
        const int k0 = kk * 32;
#pragma unroll
        for (int jj = 0; jj < 2; ++jj) {
            int row = (w * 2 + jj) * 16 + srow;
            glds16(&A[(size_t)(m0 + row) * 1024 + k0 + scol], &As[(w * 2 + jj) * 512]);
            glds16(&Bw[(size_t)(n0 + row) * 1024 + k0 + scol], &Bs[(w * 2 + jj) * 512]);
        }
        __syncthreads();
        short8 af[4], bf[4];
#pragma unroll
        for (int mt = 0; mt < 4; ++mt) af[mt] = *(const short8*)&As[(wr + mt * 16 + l15) * 32 + quad * 8];
#pragma unroll
        for (int nt = 0; nt < 4; ++nt) bf[nt] = *(const short8*)&Bs[(wc + nt * 16 + l15) * 32 + quad * 8];
#pragma unroll
        for (int mt = 0; mt < 4; ++mt)
#pragma unroll
            for (int nt = 0; nt < 4; ++nt)
                acc[mt][nt] = __builtin_amdgcn_mfma_f32_16x16x32_bf16(af[mt], bf[nt], acc[mt][nt], 0, 0, 0);
        __syncthreads();
    }
#pragma unroll
    for (int mt = 0; mt < 4; ++mt) {
#pragma unroll
        for (int nt = 0; nt < 4; ++nt) {
            int n = n0 + wc + nt * 16 + l15;
#pragma unroll
            for (int r = 0; r < 4; ++r) {
                int m = m0 + wr + mt * 16 + quad * 4 + r;
                C[(size_t)m * 1024 + n] = scale * acc[mt][nt][r] + bias[n];
            }
        }
    }
}

extern "C" void kernel_launch(void* const* d_in, const int* in_sizes, int n_in,
                              void* d_out, int out_size, void* d_ws, size_t ws_size,
                              hipStream_t stream)
{
    const float* hs = (const float*)d_in[0];
    const float* qw = (const float*)d_in[1];
    const float* qb = (const float*)d_in[2];
    const float* kw = (const float*)d_in[3];
    const float* kb = (const float*)d_in[4];
    const float* vw = (const float*)d_in[5];
    const float* vb = (const float*)d_in[6];
    const float* ow = (const float*)d_in[7];
    const float* ob = (const float*)d_in[8];
    const int*   mask = (const int*)d_in[9];
    float* out = (float*)d_out;

    const size_t MB = 1024 * 1024;
    char* ws = (char*)d_ws;
    dim3 blk(256);

    if (ws_size >= 50 * MB) {
        unsigned short* hsb = (unsigned short*)(ws);            // 8MB; later final O
        unsigned short* Q   = (unsigned short*)(ws + 8 * MB);
        unsigned short* Kp  = (unsigned short*)(ws + 16 * MB);
        unsigned short* Vt  = (unsigned short*)(ws + 24 * MB);
        unsigned short* qwb = (unsigned short*)(ws + 32 * MB);
        unsigned short* kwb = (unsigned short*)(ws + 34 * MB);
        unsigned short* vwb = (unsigned short*)(ws + 36 * MB);
        unsigned short* owb = (unsigned short*)(ws + 38 * MB);
        float* entp         = (float*)(ws + 40 * MB);
        unsigned short* O   = hsb;                              // normalized O (in-place over hsb)

        cvt5<<<dim3(8192), blk, 0, stream>>>(hs, qw, kw, vw, ow, hsb, qwb, kwb, vwb, owb, entp);
        gemm_qkv<<<dim3(512), blk, 0, stream>>>(hsb, qwb, kwb, vwb, qb, kb, vb, Q, Kp, Vt);
        flash_full<<<dim3(512), blk, 0, stream>>>(Q, Kp, Vt, mask, O, entp);
        gemm_out_bf<<<dim3(256), blk, 0, stream>>>(O, owb, ob, entp, out);
    } else {
        // diagnostic: clean zero output instead of OOB fault
        zero_out_f32<<<dim3((out_size + 255) / 256), blk, 0, stream>>>(out, out_size);
    }
}

// Round 12
// 202.795 us; speedup vs baseline: 1.0355x; 1.0331x over previous
//
#include <hip/hip_runtime.h>
#include <hip/hip_bf16.h>
#include <stdint.h>

// ResonanceAttention on MI355X (gfx950) — round 21.
// R19/R20 post-mortem: QK-fusion regressed ~6us in BOTH block orderings ->
// fusion verdict final (3-stream staging + 24KB LDS costs > barrier savings).
// R21: REVERT gemm_qkv to R18's separate-op version (best total 203.9).
// One tripwired addition: gemm_out 128x128/256blk (1 blk/CU = 1 wave/SIMD,
// most latency-starved kernel) -> 128x64/512blk = 2 blk/CU, XCD m-band kept
// (O-panel 1MB + ow 2MB = 3MB < 4MB L2). Tripwire: total>206 -> revert.
// Pipeline: cvt5 -> gemm_qkv -> flash_full -> gemm_out_bf.

#define PRIME_SCALE 0.047245559126654356f  // 1/sqrt(7*64)
#define LOG2E       1.4426950408889634f
#define LN2         0.6931471805599453f
#define QSCALE      (PRIME_SCALE * LOG2E)  // Q pre-scaled so softmax uses exp2
#define BLEND_C     0.85096556f            // closed form of the MAX_ITERS recurrence

#if __has_builtin(__builtin_amdgcn_exp2f)
#define EXP2(x) __builtin_amdgcn_exp2f(x)   // raw v_exp_f32 (1 ulp), no libm fixups
#else
#define EXP2(x) exp2f(x)
#endif

typedef __attribute__((ext_vector_type(8))) short short8;
typedef __attribute__((ext_vector_type(4))) float f32x4;

__device__ __forceinline__ unsigned short f2bf(float x) {       // RNE (GEMM epilogues)
    union { float f; unsigned int u; } v; v.f = x;
    unsigned int r = (v.u + 0x7fffu + ((v.u >> 16) & 1u)) >> 16;
    return (unsigned short)r;
}
__device__ __forceinline__ unsigned short f2bf_fast(float x) {  // round-half-up, 2 ops
    union { float f; unsigned int u; } v; v.f = x;
    return (unsigned short)((v.u + 0x8000u) >> 16);
}
__device__ __forceinline__ float bf2f(unsigned short x) {
    union { unsigned int u; float f; } v; v.u = ((unsigned int)x) << 16;
    return v.f;
}
// packed f32x2 -> bf16x2 (no builtin on gfx950 — inline asm per guide m240)
__device__ __forceinline__ unsigned cvtpk_bf16(float lo, float hi) {
    unsigned r;
    asm("v_cvt_pk_bf16_f32 %0, %1, %2" : "=v"(r) : "v"(lo), "v"(hi));
    return r;
}

// async global->LDS, 16B per lane; LDS dest = wave-uniform base + lane*16 [m97]
__device__ __forceinline__ void glds16(const unsigned short* g, unsigned short* l) {
    __builtin_amdgcn_global_load_lds((const __attribute__((address_space(1))) unsigned int*)g,
                                     (__attribute__((address_space(3))) unsigned int*)l,
                                     16, 0, 0);
}

__global__ void zero_out_f32(float* p, int n) {
    int i = blockIdx.x * 256 + threadIdx.x;
    if (i < n) p[i] = 0.f;
}

// ---------------------------------------------------------------------------
// cvt5: fp32 -> bf16 for hs (4M elems) + qw/kw/vw/ow (1M each). Zeros entp.
// ---------------------------------------------------------------------------
__global__ __launch_bounds__(256) void cvt5(
    const float* __restrict__ s0, const float* __restrict__ s1, const float* __restrict__ s2,
    const float* __restrict__ s3, const float* __restrict__ s4,
    unsigned short* __restrict__ d0, unsigned short* __restrict__ d1, unsigned short* __restrict__ d2,
    unsigned short* __restrict__ d3, unsigned short* __restrict__ d4, float* entp)
{
    if (blockIdx.x == 0 && threadIdx.x == 0) entp[0] = 0.f;
    unsigned int i = blockIdx.x * 256 + threadIdx.x;   // float4 group index, total 2^21
    const float* s; unsigned short* d; unsigned int off;
    if (i < (1u << 20)) { s = s0; d = d0; off = i; }
    else {
        unsigned int j = i - (1u << 20);
        unsigned int sel = j >> 18; off = j & 0x3FFFFu;
        s = sel == 0 ? s1 : sel == 1 ? s2 : sel == 2 ? s3 : s4;
        d = sel == 0 ? d1 : sel == 1 ? d2 : sel == 2 ? d3 : d4;
    }
    float4 v = ((const float4*)s)[off];
    ushort4 p; p.x = f2bf(v.x); p.y = f2bf(v.y); p.z = f2bf(v.z); p.w = f2bf(v.w);
    ((ushort4*)d)[off] = p;
}

// ---------------------------------------------------------------------------
// Fused Q/K/Vt GEMM (R18 version): 768 blocks, XCD-partitioned block map —
// bid = i*8 + xcd; each XCD owns one (op, m-band): A-panel 1MB + B 2MB < 4MB L2.
// ---------------------------------------------------------------------------
__global__ __launch_bounds__(256) void gemm_qkv(
    const unsigned short* __restrict__ hsb,
    const unsigned short* __restrict__ qwb, const unsigned short* __restrict__ kwb,
    const unsigned short* __restrict__ vwb,
    const float* __restrict__ qb, const float* __restrict__ kb, const float* __restrict__ vb,
    unsigned short* __restrict__ Qo, unsigned short* __restrict__ Ko, unsigned short* __restrict__ Vto)
{
    const int bid = blockIdx.x;
    const int x = bid & 7;              // XCD (HW round-robins bid%8)
    const int i = bid >> 3;             // 0..95
    const int op = i >> 5;              // 0..2
    const int j = i & 31;               // 0..31
    const unsigned short *A, *B; const float* bias; unsigned short* C;
    int m0, n0, ldc, biasRow; float scale;
    if (op == 0)      { A = hsb; B = qwb; bias = qb; C = Qo;
                        m0 = (x * 4 + (j >> 3)) * 128; n0 = (j & 7) * 128;  ldc = 1024; biasRow = 0; scale = QSCALE; }
    else if (op == 1) { A = hsb; B = kwb; bias = kb; C = Ko;
                        m0 = (x * 4 + (j >> 3)) * 128; n0 = (j & 7) * 128;  ldc = 1024; biasRow = 0; scale = 1.f; }
    else              { A = vwb; B = hsb; bias = vb; C = Vto;
                        m0 = (j & 7) * 128; n0 = (x * 4 + (j >> 3)) * 128;  ldc = 4096; biasRow = 1; scale = 1.f; }

    __shared__ unsigned short As[128 * 32];
    __shared__ unsigned short Bs[128 * 32];
    const int t = threadIdx.x, lane = t & 63, w = t >> 6;
    const int quad = lane >> 4, l15 = lane & 15;
    const int wr = (w >> 1) * 64, wc = (w & 1) * 64;
    const int srow = lane >> 2, scol = (lane & 3) * 8;

    f32x4 acc[4][4];
#pragma unroll
    for (int ii = 0; ii < 4; ++ii)
#pragma unroll
        for (int jj = 0; jj < 4; ++jj) acc[ii][jj] = (f32x4){0.f, 0.f, 0.f, 0.f};

    for (int kk = 0; kk < 32; ++kk) {
        const int k0 = kk * 32;
#pragma unroll
        for (int jj = 0; jj < 2; ++jj) {
            int row = (w * 2 + jj) * 16 + srow;
            glds16(&A[(size_t)(m0 + row) * 1024 + k0 + scol], &As[(w * 2 + jj) * 512]);
            glds16(&B[(size_t)(n0 + row) * 1024 + k0 + scol], &Bs[(w * 2 + jj) * 512]);
        }
        __syncthreads();
        short8 af[4], bf[4];
#pragma unroll
        for (int mt = 0; mt < 4; ++mt) af[mt] = *(const short8*)&As[(wr + mt * 16 + l15) * 32 + quad * 8];
#pragma unroll
        for (int nt = 0; nt < 4; ++nt) bf[nt] = *(const short8*)&Bs[(wc + nt * 16 + l15) * 32 + quad * 8];
#pragma unroll
        for (int mt = 0; mt < 4; ++mt)
#pragma unroll
            for (int nt = 0; nt < 4; ++nt)
                acc[mt][nt] = __builtin_amdgcn_mfma_f32_16x16x32_bf16(af[mt], bf[nt], acc[mt][nt], 0, 0, 0);
        __syncthreads();
    }
#pragma unroll
    for (int mt = 0; mt < 4; ++mt) {
#pragma unroll
        for (int nt = 0; nt < 4; ++nt) {
            int n = n0 + wc + nt * 16 + l15;
#pragma unroll
            for (int r = 0; r < 4; ++r) {
                int m = m0 + wr + mt * 16 + quad * 4 + r;
                float bval = biasRow ? bias[m] : bias[n];
                C[(size_t)m * ldc + n] = f2bf((acc[mt][nt][r] + bval) * scale);
            }
        }
    }
}

// ---------------------------------------------------------------------------
// flash_full: full-k flash (32 k-tiles). 128-q blocks (st=2), grid 512 =
// 2 blk/CU. Epilogue: normalize O from fp32 accs (exact 1/l), per-row
// entropy reduced to ONE atomicAdd per block.
// ---------------------------------------------------------------------------

#define STAGE(KT, BUF) do {                                                         \
    int kn_ = (KT) * 64;                                                            \
    _Pragma("unroll")                                                               \
    for (int i_ = 0; i_ < 2; ++i_) {                                                \
        int row_ = w * 16 + i_ * 8 + r8;                                            \
        int c_ = ch8 ^ (row_ & 7);                                                  \
        glds16(&K[(size_t)(b * 2048 + kn_ + row_) * 1024 + h * 64 + c_ * 8],        \
               &Ks[BUF][(w * 16 + i_ * 8) * 64]);                                   \
        glds16(&Vt[(size_t)(h * 64 + row_) * 4096 + b * 2048 + kn_ + c_ * 8],       \
               &Vs[BUF][(w * 16 + i_ * 8) * 64]);                                   \
    }                                                                               \
} while (0)

// QK^T + softmax phase; MASKED is a compile-time 0/1 (tile-uniform branch).
#define QK_SOFTMAX(MASKED)                                                          \
    _Pragma("unroll")                                                               \
    for (int nt = 0; nt < 4; ++nt) {                                                \
        int krow = nt * 16 + l15;                                                   \
        short8 kf0 = *(const short8*)&Ks[cur][krow * 64 + ((quad ^ (krow & 7)) * 8)];       \
        short8 kf1 = *(const short8*)&Ks[cur][krow * 64 + (((quad + 4) ^ (krow & 7)) * 8)]; \
        f32x4 sv[2];                                                                \
        __builtin_amdgcn_s_setprio(1);                                              \
        _Pragma("unroll")                                                           \
        for (int st = 0; st < 2; ++st) {                                            \
            sv[st] = __builtin_amdgcn_mfma_f32_16x16x32_bf16(kf0, qa[st][0], (f32x4){0.f, 0.f, 0.f, 0.f}, 0, 0, 0); \
            sv[st] = __builtin_amdgcn_mfma_f32_16x16x32_bf16(kf1, qa[st][1], sv[st], 0, 0, 0); \
        }                                                                           \
        __builtin_amdgcn_s_setprio(0);                                              \
        unsigned mb = 0xFu;                                                         \
        if (MASKED) {                                                               \
            unsigned mw = (nt & 2) ? mwB : mwA;                                     \
            mb = (mw >> (((nt & 1) << 4) + (quad << 2))) & 0xFu;                    \
        }                                                                           \
        _Pragma("unroll")                                                           \
        for (int st = 0; st < 2; ++st) {                                            \
            float s0 = sv[st][0], s1 = sv[st][1], s2 = sv[st][2], s3 = sv[st][3];   \
            if (MASKED) {                                                           \
                s0 = (mb & 1u) ? s0 : -1.0e30f;                                     \
                s1 = (mb & 2u) ? s1 : -1.0e30f;                                     \
                s2 = (mb & 4u) ? s2 : -1.0e30f;                                     \
                s3 = (mb & 8u) ? s3 : -1.0e30f;                                     \
            }                                                                       \
            float p0 = EXP2(s0), p1 = EXP2(s1), p2 = EXP2(s2), p3 = EXP2(s3);       \
            l_r[st] += (p0 + p1) + (p2 + p3);                                       \
            T_r[st] += (p0 * s0 + p1 * s1) + (p2 * s2 + p3 * s3);                   \
            pk[nt][st][0] = cvtpk_bf16(p0, p1);                                     \
            pk[nt][st][1] = cvtpk_bf16(p2, p3);                                     \
        }                                                                           \
    }

__global__ __launch_bounds__(256, 2) void flash_full(
    const unsigned short* __restrict__ Q,
    const unsigned short* __restrict__ K,
    const unsigned short* __restrict__ Vt,
    const int* __restrict__ mask,
    unsigned short* __restrict__ O,
    float* __restrict__ entp)
{
    // XCD swizzle: ww = (bid&7)*64 + bid>>3. All 16 qt of a bh on one XCD;
    // 4 bh/XCD -> K/V footprint 2MB < 4MB L2.
    const int ww = ((blockIdx.x & 7) << 6) + (blockIdx.x >> 3);
    const int qt = ww & 15;             // 0..15, 128 q-rows each
    const int bh = ww >> 4;             // 0..31
    const int b = bh >> 4, h = bh & 15;
    const int t = threadIdx.x, lane = t & 63, w = t >> 6;
    const int quad = lane >> 4, l15 = lane & 15;
    const int r8 = lane >> 3, ch8 = lane & 7;

    __shared__ __align__(16) unsigned short Ks[2][64 * 64];
    __shared__ __align__(16) unsigned short Vs[2][64 * 64];
    __shared__ unsigned int maskBits[64];        // 32 tiles x 2 words
    __shared__ float went[4];

    // Q fragments straight from global (16B per lane, once). Issued FIRST so
    // the in-loop vmcnt stream counts only glds16 (4/tile).
    short8 qa[2][2];
#pragma unroll
    for (int st = 0; st < 2; ++st) {
        size_t qrow = (size_t)(b * 2048 + qt * 128 + w * 32 + st * 16 + l15) * 1024 + h * 64;
        union { uint4 v; short8 s8; } u0, u1;
        u0.v = *(const uint4*)&Q[qrow + quad * 8];
        u1.v = *(const uint4*)&Q[qrow + 32 + quad * 8];
        qa[st][0] = u0.s8; qa[st][1] = u1.s8;
    }

    {   // bit-pack whole mask row (thread t packs 8 ints -> 1 byte), all 32 tiles
        const int4* mp = (const int4*)(mask + b * 2048 + t * 8);
        int4 a = mp[0], c = mp[1];
        unsigned bits = (unsigned)(a.x != 0)       | ((unsigned)(a.y != 0) << 1)
                      | ((unsigned)(a.z != 0) << 2) | ((unsigned)(a.w != 0) << 3)
                      | ((unsigned)(c.x != 0) << 4) | ((unsigned)(c.y != 0) << 5)
                      | ((unsigned)(c.z != 0) << 6) | ((unsigned)(c.w != 0) << 7);
        ((unsigned char*)maskBits)[t] = (unsigned char)bits;
    }

    STAGE(0, 0);
    STAGE(1, 1);

    float l_r[2] = {0.f, 0.f}, T_r[2] = {0.f, 0.f};
    f32x4 o_acc[2][4];
#pragma unroll
    for (int st = 0; st < 2; ++st)
#pragma unroll
        for (int nt = 0; nt < 4; ++nt) o_acc[st][nt] = (f32x4){0.f, 0.f, 0.f, 0.f};

    // prologue sync: maskBits visible (lgkm) + tile 0 staged (4 younger = tile 1)
    asm volatile("s_waitcnt lgkmcnt(0)" ::: "memory");
    asm volatile("s_waitcnt vmcnt(4)" ::: "memory");
    asm volatile("s_barrier" ::: "memory");

    for (int kt = 0; kt < 32; ++kt) {
        const int cur = kt & 1;
        unsigned mwA = maskBits[kt * 2], mwB = maskBits[kt * 2 + 1];

        // QK^T + softmax -> pk[nt][st][h] (P^T k-pair u32s, in registers)
        unsigned pk[4][2][2];
        if ((mwA & mwB) == 0xFFFFFFFFu) {
            QK_SOFTMAX(0)
        } else {
            QK_SOFTMAX(1)
        }

        // PV: redistribute P^T -> PV A-frags in-register, then O += P*V.
#pragma unroll
        for (int ks = 0; ks < 2; ++ks) {
            short8 pa[2];
#pragma unroll
            for (int st = 0; st < 2; ++st) {
                unsigned a0 = pk[2 * ks][st][0], a1 = pk[2 * ks][st][1];
                unsigned b0 = pk[2 * ks + 1][st][0], b1 = pk[2 * ks + 1][st][1];
                asm("v_permlane32_swap_b32 %0, %1" : "+v"(a0), "+v"(b0));
                asm("v_permlane32_swap_b32 %0, %1" : "+v"(a1), "+v"(b1));
                asm("v_permlane16_swap_b32 %0, %1" : "+v"(a0), "+v"(b0));
                asm("v_permlane16_swap_b32 %0, %1" : "+v"(a1), "+v"(b1));
                union { unsigned u[4]; short8 s8; } uu;
                uu.u[0] = a0; uu.u[1] = a1; uu.u[2] = b0; uu.u[3] = b1;
                pa[st] = uu.s8;
            }
            __builtin_amdgcn_s_setprio(1);
#pragma unroll
            for (int nt = 0; nt < 4; ++nt) {
                int vrow = nt * 16 + l15;
                short8 vf = *(const short8*)&Vs[cur][vrow * 64 + ((((ks * 4 + quad)) ^ (vrow & 7)) * 8)];
#pragma unroll
                for (int st = 0; st < 2; ++st)
                    o_acc[st][nt] = __builtin_amdgcn_mfma_f32_16x16x32_bf16(pa[st], vf, o_acc[st][nt], 0, 0, 0);
            }
            __builtin_amdgcn_s_setprio(0);
        }

        // counted-vmcnt pipeline handoff (no vmcnt(0) in steady state)
        if (kt < 31) {
            asm volatile("s_barrier" ::: "memory");        // all waves done reading buf[cur]
            if (kt < 30) {
                STAGE(kt + 2, cur);                         // overwrite just-read buffer
                asm volatile("s_waitcnt vmcnt(4)" ::: "memory");   // kt+1's 4 loads retired
            } else {
                asm volatile("s_waitcnt vmcnt(0)" ::: "memory");   // tail: tile 31's loads
            }
            asm volatile("s_barrier" ::: "memory");        // staging visible to all waves
        }
    }

    // ---- epilogue: normalize O (exact 1/l on fp32 accs), entropy in-kernel ----
    float ent_acc = 0.f;
#pragma unroll
    for (int st = 0; st < 2; ++st) {
        float l = l_r[st], T = T_r[st];
        l += __shfl_xor(l, 16); T += __shfl_xor(T, 16);
        l += __shfl_xor(l, 32); T += __shfl_xor(T, 32);
        // every lane now holds full l,T for q-row (st*16 + l15)
        ent_acc += __log2f(l) - T / l;
        float inv[4];
#pragma unroll
        for (int r = 0; r < 4; ++r)
            inv[r] = 1.0f / __shfl(l, quad * 4 + r);   // l of row quad*4+r
#pragma unroll
        for (int r = 0; r < 4; ++r) {
            int mrow = b * 2048 + qt * 128 + w * 32 + st * 16 + quad * 4 + r;
#pragma unroll
            for (int nt = 0; nt < 4; ++nt)
                O[(size_t)mrow * 1024 + h * 64 + nt * 16 + l15] = f2bf_fast(o_acc[st][nt][r] * inv[r]);
        }
    }
    // ent_acc: rows st*16+l15 summed over st; identical across quads. Reduce
    // over l15 -> sum of this wave's 32 rows; 1 atomic per block.
    ent_acc += __shfl_xor(ent_acc, 1);
    ent_acc += __shfl_xor(ent_acc, 2);
    ent_acc += __shfl_xor(ent_acc, 4);
    ent_acc += __shfl_xor(ent_acc, 8);
    if (lane == 0) went[w] = ent_acc;
    __syncthreads();
    if (t == 0)
        atomicAdd(entp, LN2 * (went[0] + went[1] + went[2] + went[3]));
}

// ---------------------------------------------------------------------------
// Output GEMM bf16: out = scale_ent * (O @ ow.T) + ob, fp32 out.
// R21: 128x64 tiles, 512 blocks = 2 blk/CU (vs 1), XCD m-band kept.
// ---------------------------------------------------------------------------
__global__ __launch_bounds__(256) void gemm_out_bf(
    const unsigned short* __restrict__ A, const unsigned short* __restrict__ Bw,
    const float* __restrict__ bias, const float* __restrict__ entp,
    float* __restrict__ C)
{
    const float avg = entp[0] * (1.0f / 65536.0f);
    const float scale = (avg < 0.2f) ? 1.0f : BLEND_C;

    const int x = blockIdx.x & 7;       // XCD
    const int j = blockIdx.x >> 3;      // 0..63
    const int m0 = (x * 4 + (j >> 4)) * 128;   // m-band per XCD (32 m-tiles)
    const int n0 = (j & 15) * 64;              // 16 n-tiles of 64
    __shared__ unsigned short As[128 * 32];
    __shared__ unsigned short Bs[64 * 32];
    const int t = threadIdx.x, lane = t & 63, w = t >> 6;
    const int quad = lane >> 4, l15 = lane & 15;
    const int wr = (w >> 1) * 64, wc = (w & 1) * 32;
    const int srow = lane >> 2, scol = (lane & 3) * 8;

    f32x4 acc[4][2];
#pragma unroll
    for (int ii = 0; ii < 4; ++ii)
#pragma unroll
        for (int jj = 0; jj < 2; ++jj) acc[ii][jj] = (f32x4){0.f, 0.f, 0.f, 0.f};

    for (int kk = 0; kk < 32; ++kk) {
        const int k0 = kk * 32;
#pragma unroll
        for (int jj = 0; jj < 2; ++jj) {
            int row = (w * 2 + jj) * 16 + srow;
            glds16(&A[(size_t)(m0 + row) * 1024 + k0 + scol], &As[(w * 2 + jj) * 512]);
        }
        {
            int row = w * 16 + srow;
            glds16(&Bw[(size_t)(n0 + row) * 1024 + k0 + scol], &Bs[w * 512]);
        }
        __syncthreads();
        short8 af[4], bf[2];
#pragma unroll
        for (int mt = 0; mt < 4; ++mt) af[mt] = *(const short8*)&As[(wr + mt * 16 + l15) * 32 + quad * 8];
#pragma unroll
        for (int nt = 0; nt < 2; ++nt) bf[nt] = *(const short8*)&Bs[(wc + nt * 16 + l15) * 32 + quad * 8];
#pragma unroll
        for (int mt = 0; mt < 4; ++mt)
#pragma unroll
            for (int nt = 0; nt < 2; ++nt)
                acc[mt][nt] = __builtin_amdgcn_mfma_f32_16x16x32_bf16(af[mt], bf[nt], acc[mt][nt], 0, 0, 0);
        __syncthreads();
    }
#pragma unroll
    for (int mt = 0; mt < 4; ++mt) {
#pragma unroll
        for (int nt = 0; nt < 2; ++nt) {
            int n = n0 + wc + nt * 16 + l15;
#pragma unroll
            for (int r = 0; r < 4; ++r) {
                int m = m0 + wr + mt * 16 + quad * 4 + r;
                C[(size_t)m * 1024 + n] = scale * acc[mt][nt][r] + bias[n];
            }
        }
    }
}

extern "C" void kernel_launch(void* const* d_in, const int* in_sizes, int n_in,
                              void* d_out, int out_size, void* d_ws, size_t ws_size,
                              hipStream_t stream)
{
    const float* hs = (const float*)d_in[0];
    const float* qw = (const float*)d_in[1];
    const float* qb = (const float*)d_in[2];
    const float* kw = (const float*)d_in[3];
    const float* kb = (const float*)d_in[4];
    const float* vw = (const float*)d_in[5];
    const float* vb = (const float*)d_in[6];
    const float* ow = (const float*)d_in[7];
    const float* ob = (const float*)d_in[8];
    const int*   mask = (const int*)d_in[9];
    float* out = (float*)d_out;

    const size_t MB = 1024 * 1024;
    char* ws = (char*)d_ws;
    dim3 blk(256);

    if (ws_size >= 50 * MB) {
        unsigned short* hsb = (unsigned short*)(ws);            // 8MB; later final O
        unsigned short* Q   = (unsigned short*)(ws + 8 * MB);
        unsigned short* Kp  = (unsigned short*)(ws + 16 * MB);
        unsigned short* Vt  = (unsigned short*)(ws + 24 * MB);
        unsigned short* qwb = (unsigned short*)(ws + 32 * MB);
        unsigned short* kwb = (unsigned short*)(ws + 34 * MB);
        unsigned short* vwb = (unsigned short*)(ws + 36 * MB);
        unsigned short* owb = (unsigned short*)(ws + 38 * MB);
        float* entp         = (float*)(ws + 40 * MB);
        unsigned short* O   = hsb;                              // normalized O (in-place over hsb)

        cvt5<<<dim3(8192), blk, 0, stream>>>(hs, qw, kw, vw, ow, hsb, qwb, kwb, vwb, owb, entp);
        gemm_qkv<<<dim3(768), blk, 0, stream>>>(hsb, qwb, kwb, vwb, qb, kb, vb, Q, Kp, Vt);
        flash_full<<<dim3(512), blk, 0, stream>>>(Q, Kp, Vt, mask, O, entp);
        gemm_out_bf<<<dim3(512), blk, 0, stream>>>(O, owb, ob, entp, out);
    } else {
        // diagnostic: clean zero output instead of OOB fault
        zero_out_f32<<<dim3((out_size + 255) / 256), blk, 0, stream>>>(out, out_size);
    }
}